// Round 5
// baseline (289.278 us; speedup 1.0000x reference)
//
#include <hip/hip_runtime.h>

// SpatialTransformer3D: B=2, H=W=D=128, C=4.
// out[b,i,j,k,:] = trilinear sample of image[b] at c = t*grid, t in [0,1).
// Octant q -> XCD q (blockIdx%8 round-robin): each XCD's gather working set
// is one 64^3 octant = 4.19 MB ~= its private L2. (R4: FETCH 287->55 MB.)
// R5: V=2 voxels/thread (same octant, jp and jp+4), phase-split so all 16
// gathers are in flight together -> tests MSHR-concurrency vs issue-bound.

typedef float f4 __attribute__((ext_vector_type(4)));

__global__ __launch_bounds__(256) void st3d_kernel(
    const float* __restrict__ img,     // (B,128,128,128,4)
    const float* __restrict__ trans,   // (B,128,128,128,3)
    f4* __restrict__ out)              // (B,128,128,128,4) as f4
{
    constexpr int V = 2;
    // 8192 blocks: q = octant/XCD, n = 0..1023 per octant
    int bid = blockIdx.x;
    int q   = bid & 7;
    int n   = bid >> 3;                // 0..1023
    int b   = n >> 9;                  // batch (0..1)
    int m0  = ((n & 511) << 9) | threadIdx.x;   // voxel A index in octant

    int qi = (q >> 2) & 1;
    int qj = (q >> 1) & 1;
    int qk = q & 1;

    int   idxv[V];
    int   A0[V], A1[V], A2[V], A3[V];
    int   dzi[V];
    float w000[V], w100[V], w010[V], w110[V];
    float w001[V], w101[V], w011[V], w111[V];

    // ---- Phase 1: trans loads + address/weight math for both voxels ----
#pragma unroll
    for (int v = 0; v < V; ++v) {
        int m = m0 + v * 256;          // voxel B: jp + 4 (same octant)
        int kp = m & 63;
        int jp = (m >> 6) & 63;
        int ip = m >> 12;

        // sweep i center-outward so the L2 working set grows from ~0
        int ipe = qi ? ip : (63 - ip);
        int i = (qi << 6) + ipe;
        int j = (qj << 6) + jp;
        int k = (qk << 6) + kp;

        int idx = (((b << 7) | i) << 14) | (j << 7) | k;
        idxv[v] = idx;

        const float step = 2.0f / 127.0f;
        float gx = -1.0f + step * (float)j;
        float gy = -1.0f + step * (float)i;
        float gz = -1.0f + step * (float)k;

        const float* t = trans + (size_t)idx * 3;
        float tx = __builtin_nontemporal_load(t + 0);
        float ty = __builtin_nontemporal_load(t + 1);
        float tz = __builtin_nontemporal_load(t + 2);

        float x = (tx * gx + 1.0f) * 64.0f;
        float y = (ty * gy + 1.0f) * 64.0f;
        float z = (tz * gz + 1.0f) * 64.0f;

        int x0 = (int)floorf(x);
        int y0 = (int)floorf(y);
        int z0 = (int)floorf(z);
        int x1 = min(max(x0 + 1, 0), 127);
        int y1 = min(max(y0 + 1, 0), 127);
        int z1 = min(max(z0 + 1, 0), 127);
        x0 = min(max(x0, 0), 127);
        y0 = min(max(y0, 0), 127);
        z0 = min(max(z0, 0), 127);

        float dx = (float)x1 - x;
        float dy = (float)y1 - y;
        float dz = (float)z1 - z;
        float ex = 1.0f - dx;
        float ey = 1.0f - dy;
        float ez = 1.0f - dz;

        int bb  = b << 21;
        int ry0 = bb + (y0 << 14);
        int ry1 = bb + (y1 << 14);
        int cx0 = x0 << 7;
        int cx1 = x1 << 7;

        A0[v] = ry0 + cx0 + z0;
        A1[v] = ry1 + cx0 + z0;
        A2[v] = ry0 + cx1 + z0;
        A3[v] = ry1 + cx1 + z0;
        dzi[v] = z1 - z0;

        w000[v] = dz * dx * dy;
        w100[v] = dz * dx * ey;
        w010[v] = dz * ex * dy;
        w110[v] = dz * ex * ey;
        w001[v] = ez * dx * dy;
        w101[v] = ez * dx * ey;
        w011[v] = ez * ex * dy;
        w111[v] = ez * ex * ey;
    }

    // ---- Phase 2: all 16 gathers in flight ----
    const f4* img4 = (const f4*)img;
    f4 c[V][8];
#pragma unroll
    for (int v = 0; v < V; ++v) {
        c[v][0] = img4[A0[v]];
        c[v][1] = img4[A1[v]];
        c[v][2] = img4[A2[v]];
        c[v][3] = img4[A3[v]];
        c[v][4] = img4[A0[v] + dzi[v]];
        c[v][5] = img4[A1[v] + dzi[v]];
        c[v][6] = img4[A2[v] + dzi[v]];
        c[v][7] = img4[A3[v] + dzi[v]];
    }

    // ---- Phase 3: weighted sums + stores ----
#pragma unroll
    for (int v = 0; v < V; ++v) {
        f4 o = w000[v]*c[v][0] + w100[v]*c[v][1] + w010[v]*c[v][2] + w110[v]*c[v][3]
             + w001[v]*c[v][4] + w101[v]*c[v][5] + w011[v]*c[v][6] + w111[v]*c[v][7];
        __builtin_nontemporal_store(o, &out[idxv[v]]);
    }
}

extern "C" void kernel_launch(void* const* d_in, const int* in_sizes, int n_in,
                              void* d_out, int out_size, void* d_ws, size_t ws_size,
                              hipStream_t stream) {
    const float* img   = (const float*)d_in[0];
    const float* trans = (const float*)d_in[1];
    f4* out = (f4*)d_out;

    int N = in_sizes[1] / 3;           // B*128^3 = 4,194,304 voxels
    int block = 256;
    int grid = N / (block * 2);        // 8192 blocks
    st3d_kernel<<<grid, block, 0, stream>>>(img, trans, out);
}

// Round 6
// 237.999 us; speedup vs baseline: 1.2155x; 1.2155x over previous
//
#include <hip/hip_runtime.h>
#include <hip/hip_fp16.h>

// SpatialTransformer3D: B=2, H=W=D=128, C=4.
// out[b,i,j,k,:] = trilinear sample of image[b] at c = t*grid, t in [0,1).
//
// R6: the kernel is pinned at ~180 us across all locality/MLP variants ->
// model: per-CU divergent-gather crack rate (per-lane sub-requests at TA/TCP).
// Lever: fp16 image copy (pre-pass into d_ws). A corner (x,y)-pair's z0,z1
// data (8 halfs = 16 B contiguous) becomes ONE dwordx4 gather -> 4 gathers
// per voxel instead of 8. Octant q -> XCD q map kept (FETCH 287->55 MB in R4).

typedef float f4 __attribute__((ext_vector_type(4)));
typedef unsigned int u32;
typedef u32 u4v __attribute__((ext_vector_type(4), aligned(8)));

__device__ inline float2 h2f(u32 b) {
    __half2 h = __builtin_bit_cast(__half2, b);
    return __half22float2(h);
}

// ---- Pass 1: fp32 image -> fp16 copy in workspace (same layout) ----
__global__ __launch_bounds__(256) void cvt_kernel(
    const f4* __restrict__ img, uint2* __restrict__ himg)
{
    int idx = blockIdx.x * 256 + threadIdx.x;   // f4 index, 0 .. B*128^3-1
    f4 v = img[idx];
    __half2 lo = __floats2half2_rn(v.x, v.y);
    __half2 hi = __floats2half2_rn(v.z, v.w);
    himg[idx] = make_uint2(__builtin_bit_cast(u32, lo), __builtin_bit_cast(u32, hi));
}

// ---- Pass 2: main sample kernel (fp16 gathers) ----
__global__ __launch_bounds__(256) void st3d_h_kernel(
    const u32* __restrict__ himg,      // (B,128,128,128,4) fp16
    const float* __restrict__ trans,   // (B,128,128,128,3) fp32
    f4* __restrict__ out)              // (B,128,128,128,4) fp32
{
    // octant q -> XCD q via blockIdx%8 round-robin
    int bid = blockIdx.x;
    int q   = bid & 7;
    int n   = bid >> 3;                 // 0..2047
    int b   = n >> 10;
    int m   = ((n & 1023) << 8) | threadIdx.x;

    int kp = m & 63;
    int jp = (m >> 6) & 63;
    int ip = m >> 12;

    int qi = (q >> 2) & 1;
    int qj = (q >> 1) & 1;
    int qk = q & 1;

    int ipe = qi ? ip : (63 - ip);      // center-outward sweep
    int i = (qi << 6) + ipe;
    int j = (qj << 6) + jp;
    int k = (qk << 6) + kp;

    int idx = (((b << 7) | i) << 14) | (j << 7) | k;

    const float step = 2.0f / 127.0f;
    float gx = -1.0f + step * (float)j;
    float gy = -1.0f + step * (float)i;
    float gz = -1.0f + step * (float)k;

    const float* t = trans + (size_t)idx * 3;
    float tx = __builtin_nontemporal_load(t + 0);
    float ty = __builtin_nontemporal_load(t + 1);
    float tz = __builtin_nontemporal_load(t + 2);

    float x = (tx * gx + 1.0f) * 64.0f;
    float y = (ty * gy + 1.0f) * 64.0f;
    float z = (tz * gz + 1.0f) * 64.0f;

    int x0 = (int)floorf(x);
    int y0 = (int)floorf(y);
    int z0 = (int)floorf(z);
    int x1 = min(max(x0 + 1, 0), 127);
    int y1 = min(max(y0 + 1, 0), 127);
    int z1 = min(max(z0 + 1, 0), 127);
    x0 = min(max(x0, 0), 127);
    y0 = min(max(y0, 0), 127);
    z0 = min(max(z0, 0), 127);

    // weights use CLIPPED upper corners (reference semantics)
    float dx = (float)x1 - x;
    float dy = (float)y1 - y;
    float dz = (float)z1 - z;
    float ex = 1.0f - dx;
    float ey = 1.0f - dy;
    float ez = 1.0f - dz;

    int zb = min(z0, 126);              // pair base; 16B window covers zb, zb+1
    int i0 = z0 - zb;                   // 0 normally; 1 only when z0 == 127
    int i1 = z1 - zb;                   // 1 normally

    int bb  = b << 21;
    int ry0 = bb + (y0 << 14);
    int ry1 = bb + (y1 << 14);
    int cx0 = x0 << 7;
    int cx1 = x1 << 7;

    // u32 index = f4_index * 2 (4 halfs per voxel-channel-quad = 2 dwords)
    const u4v* p0 = (const u4v*)(himg + (size_t)(ry0 + cx0 + zb) * 2);
    const u4v* p1 = (const u4v*)(himg + (size_t)(ry1 + cx0 + zb) * 2);
    const u4v* p2 = (const u4v*)(himg + (size_t)(ry0 + cx1 + zb) * 2);
    const u4v* p3 = (const u4v*)(himg + (size_t)(ry1 + cx1 + zb) * 2);

    // all 4 gathers in flight
    u4v d0 = *p0;
    u4v d1 = *p1;
    u4v d2 = *p2;
    u4v d3 = *p3;

    // per-pair (z0-weight, z1-weight); pairing matches reference terms
    float wA0 = dz * dx * dy, wB0 = ez * dx * dy;   // (y0,x0)
    float wA1 = dz * dx * ey, wB1 = ez * dx * ey;   // (y1,x0)
    float wA2 = dz * ex * dy, wB2 = ez * ex * dy;   // (y0,x1)
    float wA3 = dz * ex * ey, wB3 = ez * ex * ey;   // (y1,x1)

    float ox = 0.f, oy = 0.f, oz = 0.f, ow = 0.f;

#define ACC(d, wA, wB)                                            \
    {                                                             \
        u32 a0 = i0 ? (d).z : (d).x;  /* c0c1 @ z0 */             \
        u32 a1 = i0 ? (d).w : (d).y;  /* c2c3 @ z0 */             \
        u32 b0 = i1 ? (d).z : (d).x;  /* c0c1 @ z1 */             \
        u32 b1 = i1 ? (d).w : (d).y;  /* c2c3 @ z1 */             \
        float2 fa0 = h2f(a0), fa1 = h2f(a1);                      \
        float2 fb0 = h2f(b0), fb1 = h2f(b1);                      \
        ox += (wA) * fa0.x + (wB) * fb0.x;                        \
        oy += (wA) * fa0.y + (wB) * fb0.y;                        \
        oz += (wA) * fa1.x + (wB) * fb1.x;                        \
        ow += (wA) * fa1.y + (wB) * fb1.y;                        \
    }

    ACC(d0, wA0, wB0)
    ACC(d1, wA1, wB1)
    ACC(d2, wA2, wB2)
    ACC(d3, wA3, wB3)
#undef ACC

    f4 o = {ox, oy, oz, ow};
    __builtin_nontemporal_store(o, &out[idx]);
}

// ---- Fallback (proven R4 fp32 kernel) if workspace is too small ----
__global__ __launch_bounds__(256) void st3d_kernel(
    const float* __restrict__ img,
    const float* __restrict__ trans,
    f4* __restrict__ out)
{
    int bid = blockIdx.x;
    int q   = bid & 7;
    int n   = bid >> 3;
    int b   = n >> 10;
    int m   = ((n & 1023) << 8) | threadIdx.x;

    int kp = m & 63;
    int jp = (m >> 6) & 63;
    int ip = m >> 12;

    int qi = (q >> 2) & 1;
    int qj = (q >> 1) & 1;
    int qk = q & 1;

    int ipe = qi ? ip : (63 - ip);
    int i = (qi << 6) + ipe;
    int j = (qj << 6) + jp;
    int k = (qk << 6) + kp;

    int idx = (((b << 7) | i) << 14) | (j << 7) | k;

    const float step = 2.0f / 127.0f;
    float gx = -1.0f + step * (float)j;
    float gy = -1.0f + step * (float)i;
    float gz = -1.0f + step * (float)k;

    const float* t = trans + (size_t)idx * 3;
    float tx = __builtin_nontemporal_load(t + 0);
    float ty = __builtin_nontemporal_load(t + 1);
    float tz = __builtin_nontemporal_load(t + 2);

    float x = (tx * gx + 1.0f) * 64.0f;
    float y = (ty * gy + 1.0f) * 64.0f;
    float z = (tz * gz + 1.0f) * 64.0f;

    int x0 = (int)floorf(x);
    int y0 = (int)floorf(y);
    int z0 = (int)floorf(z);
    int x1 = min(max(x0 + 1, 0), 127);
    int y1 = min(max(y0 + 1, 0), 127);
    int z1 = min(max(z0 + 1, 0), 127);
    x0 = min(max(x0, 0), 127);
    y0 = min(max(y0, 0), 127);
    z0 = min(max(z0, 0), 127);

    float dx = (float)x1 - x;
    float dy = (float)y1 - y;
    float dz = (float)z1 - z;
    float ex = 1.0f - dx;
    float ey = 1.0f - dy;
    float ez = 1.0f - dz;

    const f4* img4 = (const f4*)img;
    int bb  = b << 21;
    int ry0 = bb + (y0 << 14);
    int ry1 = bb + (y1 << 14);
    int cx0 = x0 << 7;
    int cx1 = x1 << 7;

    int A0 = ry0 + cx0 + z0;
    int A1 = ry1 + cx0 + z0;
    int A2 = ry0 + cx1 + z0;
    int A3 = ry1 + cx1 + z0;
    int dzi = z1 - z0;

    f4 c000 = img4[A0];
    f4 c100 = img4[A1];
    f4 c010 = img4[A2];
    f4 c110 = img4[A3];
    f4 c001 = img4[A0 + dzi];
    f4 c101 = img4[A1 + dzi];
    f4 c011 = img4[A2 + dzi];
    f4 c111 = img4[A3 + dzi];

    float w000 = dz * dx * dy;
    float w100 = dz * dx * ey;
    float w010 = dz * ex * dy;
    float w110 = dz * ex * ey;
    float w001 = ez * dx * dy;
    float w101 = ez * dx * ey;
    float w011 = ez * ex * dy;
    float w111 = ez * ex * ey;

    f4 o = w000*c000 + w100*c100 + w010*c010 + w110*c110
         + w001*c001 + w101*c101 + w011*c011 + w111*c111;

    __builtin_nontemporal_store(o, &out[idx]);
}

extern "C" void kernel_launch(void* const* d_in, const int* in_sizes, int n_in,
                              void* d_out, int out_size, void* d_ws, size_t ws_size,
                              hipStream_t stream) {
    const float* img   = (const float*)d_in[0];
    const float* trans = (const float*)d_in[1];
    f4* out = (f4*)d_out;

    int N = in_sizes[1] / 3;            // B*128^3 = 4,194,304 voxels
    int block = 256;
    int grid = N / block;               // 16384 blocks

    size_t need = (size_t)N * 4 * sizeof(__half);   // 33.5 MB fp16 image
    if (ws_size >= need) {
        cvt_kernel<<<grid, block, 0, stream>>>((const f4*)img, (uint2*)d_ws);
        st3d_h_kernel<<<grid, block, 0, stream>>>((const u32*)d_ws, trans, out);
    } else {
        st3d_kernel<<<grid, block, 0, stream>>>(img, trans, out);
    }
}